// Round 6
// baseline (1302.282 us; speedup 1.0000x reference)
//
#include <hip/hip_runtime.h>
#include <cstdint>
#include <cstddef>

#define TSTEPS 512
#define INP    24
#define HID    128
#define BB     16     // batch elems per block -> N=16 mfma tile FULLY used
#define NKT    5      // K = 24 x + 128 h + 8 pad = 160 = 5 tiles of 32
#define VSTR   168    // v[] column stride in ushorts; 84 dwords -> ncol*20%32 bank skew

typedef __attribute__((ext_vector_type(8))) short short8;   // 8 x bf16 (4 VGPRs)
typedef __attribute__((ext_vector_type(4))) float f32x4;

__device__ __forceinline__ float sigm_f(float v) {
    return 1.0f / (1.0f + __expf(-v));
}
__device__ __forceinline__ float tanh_f(float v) {
    float a = fabsf(v);
    float e = __expf(-2.0f * a);
    float r = (1.0f - e) / (1.0f + e);
    return v < 0.0f ? -r : r;
}
__device__ __forceinline__ unsigned short f2bf(float f) {
    unsigned u = __float_as_uint(f);
    return (unsigned short)((u + 0x7fffu + ((u >> 16) & 1u)) >> 16);
}
__device__ __forceinline__ float bf2f(unsigned short h) {
    return __uint_as_float(((unsigned)h) << 16);
}

// ROUND LESSONS ENCODED:
//  R1: VGPR cap betrayal -> scratch spill shows as WRITE_SIZE GBs. Watch it.
//  R2: runtime-varying index into per-thread arrays demotes to memory. All
//      A-frag/acc indices are compile-time below.
//  R3: fp32 VALU path saturates ~3x too slow; use MFMA w/ split-bf16.
//  R4/R5: total time == per-block time (blocks run 1/CU concurrently); CU count
//      is irrelevant. Optimize the per-ts serial chain, not "utilization".
//  R5: per-ts x prefetch at distance-1 stalls ~900cyc on HBM misses before the
//      barrier -> everyone waits. THIS ROUND: distance-2 register queue (issue
//      x(ts+2), stage x(ts+1) at ts-top, roll the queue at ts-bottom).
//
// Per ts: gates[512x16] = W[512x160] @ v[160x16]; v = [x_t(24)|h(128)|0(8)]
// split hi/lo bf16 (3-term: err ~2^-17). mfma_f32_16x16x32_bf16:
//   A-frag: lane holds A[m=lane&15][k=quad*8+j]
//   B-frag: lane holds B[k=quad*8+j][n=lane&15]
//   C/D:    col=lane&15, row=quad*4+reg
__global__ __launch_bounds__(512) __attribute__((amdgpu_waves_per_eu(2, 2)))
void lstm_fused(
    const float* __restrict__ x,      // [B, T, 24]
    const float* __restrict__ addin,  // [B, 2]
    const float* __restrict__ W_ih,   // [512, 24]
    const float* __restrict__ W_hh,   // [512, 128]
    const float* __restrict__ b_ih,   // [512]
    const float* __restrict__ b_hh,   // [512]
    const float* __restrict__ W1,     // [64, 130]
    const float* __restrict__ b1,     // [64]
    const float* __restrict__ W2,     // [3, 64]
    const float* __restrict__ b2,     // [3]
    float* __restrict__ out)          // [B, 3]
{
    __shared__ unsigned short v_hi[2][BB * VSTR];   // [buf][n][k] bf16 hi
    __shared__ unsigned short v_lo[2][BB * VSTR];   // residual bf16
    __shared__ float z_s[BB][64];

    const int t    = threadIdx.x;      // 512 threads = 8 waves
    const int lane = t & 63;
    const int wv   = t >> 6;           // 0..7: owns units j in [wv*16, wv*16+16)
    const int ncol = lane & 15;        // batch col
    const int quad = lane >> 4;
    const int b0   = blockIdx.x * BB;
    const int j0   = wv * 16 + quad * 4;   // first of this lane's 4 units

    // ---- persistent A-fragments: gate g tile = rows g*128 + wv*16 .. +15 ----
    short8 A_hi[4][NKT], A_lo[4][NKT];
    #pragma unroll
    for (int g = 0; g < 4; ++g) {
        const int row = g * HID + wv * 16 + ncol;
        #pragma unroll
        for (int kt = 0; kt < NKT; ++kt) {
            short8 hi, lo;
            #pragma unroll
            for (int j = 0; j < 8; ++j) {
                const int k = kt * 32 + quad * 8 + j;
                float w = 0.0f;
                if (k < INP)            w = W_ih[row * INP + k];
                else if (k < INP + HID) w = W_hh[row * HID + (k - INP)];
                const unsigned short h16 = f2bf(w);
                hi[j] = (short)h16;
                lo[j] = (short)f2bf(w - bf2f(h16));
            }
            A_hi[g][kt] = hi;
            A_lo[g][kt] = lo;
        }
    }

    // per-lane biases for units j0..j0+3 (acc initializers)
    const float4 bi4 = *(const float4*)(b_ih + 0 * HID + j0);
    const float4 bf4 = *(const float4*)(b_ih + 1 * HID + j0);
    const float4 bg4 = *(const float4*)(b_ih + 2 * HID + j0);
    const float4 bo4 = *(const float4*)(b_ih + 3 * HID + j0);
    const float4 ci4 = *(const float4*)(b_hh + 0 * HID + j0);
    const float4 cf4 = *(const float4*)(b_hh + 1 * HID + j0);
    const float4 cg4 = *(const float4*)(b_hh + 2 * HID + j0);
    const float4 co4 = *(const float4*)(b_hh + 3 * HID + j0);
    const f32x4 bias_i = {bi4.x + ci4.x, bi4.y + ci4.y, bi4.z + ci4.z, bi4.w + ci4.w};
    const f32x4 bias_f = {bf4.x + cf4.x, bf4.y + cf4.y, bf4.z + cf4.z, bf4.w + cf4.w};
    const f32x4 bias_g = {bg4.x + cg4.x, bg4.y + cg4.y, bg4.z + cg4.z, bg4.w + cg4.w};
    const f32x4 bias_o = {bo4.x + co4.x, bo4.y + co4.y, bo4.z + co4.z, bo4.w + co4.w};

    // x-staging role: thread t<192 handles batch xb, k-pair kk*2
    const int xb = t / 12;
    const int kk = t - xb * 12;

    // ---- init: zero both buffers (pads k>=152 stay 0 forever), stage x(0) ----
    for (int i = t; i < BB * VSTR; i += 512) {
        v_hi[0][i] = 0; v_lo[0][i] = 0; v_hi[1][i] = 0; v_lo[1][i] = 0;
    }
    __syncthreads();
    if (t < 192) {
        const float2 xv = *(const float2*)(x + ((size_t)(b0 + xb) * TSTEPS) * INP + kk * 2);
        const unsigned short h0 = f2bf(xv.x), h1 = f2bf(xv.y);
        *(unsigned*)&v_hi[0][xb * VSTR + kk * 2] = (unsigned)h0 | ((unsigned)h1 << 16);
        *(unsigned*)&v_lo[0][xb * VSTR + kk * 2] =
            (unsigned)f2bf(xv.x - bf2f(h0)) | ((unsigned)f2bf(xv.y - bf2f(h1)) << 16);
    }
    float c0 = 0.f, c1 = 0.f, c2 = 0.f, c3 = 0.f;   // cell state, units j0..j0+3

    // prime the x register queue: xq = x(1)
    float2 xq = {0.f, 0.f};
    if (t < 192) {
        xq = *(const float2*)(x + ((size_t)(b0 + xb) * TSTEPS + 1) * INP + kk * 2);
    }
    __syncthreads();

    // ---- recurrence: ONE barrier per ts, distance-2 x prefetch ----
    for (int ts = 0; ts < TSTEPS; ++ts) {
        const int pb = ts & 1, nb = pb ^ 1;

        // issue load of x(ts+2); stage x(ts+1)=xq into nb NOW (write retires
        // long before the barrier; nobody reads nb's x-section this ts)
        float2 xn = {0.f, 0.f};
        if (t < 192) {
            const int tsn = (ts + 2 < TSTEPS) ? ts + 2 : TSTEPS - 1;
            xn = *(const float2*)(x + ((size_t)(b0 + xb) * TSTEPS + tsn) * INP + kk * 2);
            const unsigned short h0 = f2bf(xq.x), h1 = f2bf(xq.y);
            *(unsigned*)&v_hi[nb][xb * VSTR + kk * 2] = (unsigned)h0 | ((unsigned)h1 << 16);
            *(unsigned*)&v_lo[nb][xb * VSTR + kk * 2] =
                (unsigned)f2bf(xq.x - bf2f(h0)) | ((unsigned)f2bf(xq.y - bf2f(h1)) << 16);
        }

        const unsigned short* vh = v_hi[pb];
        const unsigned short* vl = v_lo[pb];
        f32x4 ai = bias_i, af = bias_f, ag = bias_g, ao = bias_o;
        #pragma unroll
        for (int kt = 0; kt < NKT; ++kt) {
            const int voff = ncol * VSTR + kt * 32 + quad * 8;
            const short8 bh = *(const short8*)(vh + voff);
            const short8 bl = *(const short8*)(vl + voff);
            ai = __builtin_amdgcn_mfma_f32_16x16x32_bf16(A_hi[0][kt], bh, ai, 0, 0, 0);
            af = __builtin_amdgcn_mfma_f32_16x16x32_bf16(A_hi[1][kt], bh, af, 0, 0, 0);
            ag = __builtin_amdgcn_mfma_f32_16x16x32_bf16(A_hi[2][kt], bh, ag, 0, 0, 0);
            ao = __builtin_amdgcn_mfma_f32_16x16x32_bf16(A_hi[3][kt], bh, ao, 0, 0, 0);
            ai = __builtin_amdgcn_mfma_f32_16x16x32_bf16(A_lo[0][kt], bh, ai, 0, 0, 0);
            af = __builtin_amdgcn_mfma_f32_16x16x32_bf16(A_lo[1][kt], bh, af, 0, 0, 0);
            ag = __builtin_amdgcn_mfma_f32_16x16x32_bf16(A_lo[2][kt], bh, ag, 0, 0, 0);
            ao = __builtin_amdgcn_mfma_f32_16x16x32_bf16(A_lo[3][kt], bh, ao, 0, 0, 0);
            ai = __builtin_amdgcn_mfma_f32_16x16x32_bf16(A_hi[0][kt], bl, ai, 0, 0, 0);
            af = __builtin_amdgcn_mfma_f32_16x16x32_bf16(A_hi[1][kt], bl, af, 0, 0, 0);
            ag = __builtin_amdgcn_mfma_f32_16x16x32_bf16(A_hi[2][kt], bl, ag, 0, 0, 0);
            ao = __builtin_amdgcn_mfma_f32_16x16x32_bf16(A_hi[3][kt], bl, ao, 0, 0, 0);
        }

        // in-register cell update: this lane owns (batch ncol, units j0+r), r=0..3
        unsigned short hh[4], hl[4];
        #define UPD(r, cr)                                                     \
        {                                                                      \
            const float gi = sigm_f(ai[r]);                                    \
            const float gf = sigm_f(af[r]);                                    \
            const float gg = tanh_f(ag[r]);                                    \
            const float go = sigm_f(ao[r]);                                    \
            cr = gf * cr + gi * gg;                                            \
            const float h = go * tanh_f(cr);                                   \
            hh[r] = f2bf(h);                                                   \
            hl[r] = f2bf(h - bf2f(hh[r]));                                     \
        }
        UPD(0, c0) UPD(1, c1) UPD(2, c2) UPD(3, c3)
        #undef UPD

        // h write: 4 consecutive bf16 -> one b64 each for hi and lo
        {
            const int hoff = ncol * VSTR + INP + j0;
            uint2 ph, pl;
            ph.x = (unsigned)hh[0] | ((unsigned)hh[1] << 16);
            ph.y = (unsigned)hh[2] | ((unsigned)hh[3] << 16);
            pl.x = (unsigned)hl[0] | ((unsigned)hl[1] << 16);
            pl.y = (unsigned)hl[2] | ((unsigned)hl[3] << 16);
            *(uint2*)&v_hi[nb][hoff] = ph;
            *(uint2*)&v_lo[nb][hoff] = pl;
        }

        // roll the x queue (vmcnt wait lands here: load was issued ~1 full ts ago)
        if (t < 192) xq = xn;
        __syncthreads();
    }

    // ---- FC head: final h is in buffer 0 (last write at ts=511 -> nb=0) ----
    #pragma unroll
    for (int pass = 0; pass < 2; ++pass) {
        const int b = (t >> 6) + pass * 8, u = t & 63;
        const float* w = W1 + u * 130;
        float a = b1[u];
        #pragma unroll 16
        for (int k = 0; k < HID; ++k) {
            const float hv = bf2f(v_hi[0][b * VSTR + INP + k]) + bf2f(v_lo[0][b * VSTR + INP + k]);
            a += fmaxf(hv, 0.0f) * w[k];
        }
        const float a0 = addin[(size_t)(b0 + b) * 2 + 0];
        const float a1 = addin[(size_t)(b0 + b) * 2 + 1];
        a += fmaxf(a0, 0.0f) * w[128] + fmaxf(a1, 0.0f) * w[129];
        z_s[b][u] = fmaxf(a, 0.0f);
    }
    __syncthreads();
    if (t < 48) {
        const int b = t / 3, o = t - 3 * b;
        const float* w = W2 + o * 64;
        float a = b2[o];
        #pragma unroll
        for (int k = 0; k < 64; ++k)
            a += z_s[b][k] * w[k];
        out[(size_t)(b0 + b) * 3 + o] = a;
    }
}

extern "C" void kernel_launch(void* const* d_in, const int* in_sizes, int n_in,
                              void* d_out, int out_size, void* d_ws, size_t ws_size,
                              hipStream_t stream) {
    const float* x     = (const float*)d_in[0];
    const float* addin = (const float*)d_in[1];
    const float* W_ih  = (const float*)d_in[2];
    const float* W_hh  = (const float*)d_in[3];
    const float* b_ih  = (const float*)d_in[4];
    const float* b_hh  = (const float*)d_in[5];
    const float* W1    = (const float*)d_in[6];
    const float* b1    = (const float*)d_in[7];
    const float* W2    = (const float*)d_in[8];
    const float* b2    = (const float*)d_in[9];
    float* outp        = (float*)d_out;

    const int B = in_sizes[0] / (TSTEPS * INP);   // 1024
    const int grid = B / BB;                      // 64 blocks

    lstm_fused<<<grid, 512, 0, stream>>>(x, addin, W_ih, W_hh, b_ih, b_hh,
                                         W1, b1, W2, b2, outp);
}

// Round 7
// 920.149 us; speedup vs baseline: 1.4153x; 1.4153x over previous
//
#include <hip/hip_runtime.h>
#include <cstdint>
#include <cstddef>

#define TSTEPS 512
#define INP    24
#define HID    128
#define BB     4      // batch elems per block; 256 blocks (1/CU)
#define NKT    5      // K = 24 x + 128 h + 8 pad = 160 = 5 tiles of 32
#define VSTR   168    // v[] column stride in ushorts
#define GB     520    // part_s batch stride in floats; 520 mod 32 == 8 -> <=2-way banks

typedef __attribute__((ext_vector_type(8))) short short8;   // 8 x bf16 (4 VGPRs)
typedef __attribute__((ext_vector_type(4))) float f32x4;

__device__ __forceinline__ float sigm_f(float v) {
    return 1.0f / (1.0f + __expf(-v));
}
__device__ __forceinline__ float tanh_f(float v) {
    float a = fabsf(v);
    float e = __expf(-2.0f * a);
    float r = (1.0f - e) / (1.0f + e);
    return v < 0.0f ? -r : r;
}
__device__ __forceinline__ unsigned short f2bf(float f) {
    unsigned u = __float_as_uint(f);
    return (unsigned short)((u + 0x7fffu + ((u >> 16) & 1u)) >> 16);
}
__device__ __forceinline__ float bf2f(unsigned short h) {
    return __uint_as_float(((unsigned)h) << 16);
}

// ROUND LESSONS ENCODED:
//  R1: VGPR cap betrayal -> scratch spill shows as WRITE_SIZE GBs. Watch it.
//  R2: runtime-varying index into per-thread arrays demotes to memory. All
//      A-frag indices compile-time below.
//  R3: fp32 VALU ~3x too slow; MFMA w/ split-bf16 (hi/lo, 3 passes, ~2^-17).
//  R4/R5: total time == per-block time (blocks run concurrently, CU count free).
//  R6: x-prefetch distance irrelevant — x-stall theory dead.
//  MODEL FIX (R6 post-mortem): mfma_16x16x32_bf16 ~19.4 cyc/SIMD (NOT 4.85 —
//      that's per-CU). 480 mfma/block/ts = 2328 cyc/SIMD matrix drain; phases
//      SUM (UPD waits on own mfmas). Validated vs R4 (4350) and R5 (5810).
//      => minimize post-MFMA work per block: BB=4 -> 512 UPDs/block, 1/thread,
//      via conflict-free LDS redistribution (NOT R5's 4-UPDs-per-lane in-reg).
//
// Per ts: gates[512 x 16] = W[512 x 160] @ v[160 x 16], batch cols 0..3 real,
// cols 4..15 permanently zero. mfma_f32_16x16x32_bf16:
//   A-frag: lane holds A[m=lane&15][k=quad*8+j]
//   B-frag: lane holds B[k=quad*8+j][n=lane&15]
//   C/D:    col=lane&15, row=quad*4+reg
__global__ __launch_bounds__(512) __attribute__((amdgpu_waves_per_eu(2, 2)))
void lstm_fused(
    const float* __restrict__ x,      // [B, T, 24]
    const float* __restrict__ addin,  // [B, 2]
    const float* __restrict__ W_ih,   // [512, 24]
    const float* __restrict__ W_hh,   // [512, 128]
    const float* __restrict__ b_ih,   // [512]
    const float* __restrict__ b_hh,   // [512]
    const float* __restrict__ W1,     // [64, 130]
    const float* __restrict__ b1,     // [64]
    const float* __restrict__ W2,     // [3, 64]
    const float* __restrict__ b2,     // [3]
    float* __restrict__ out)          // [B, 3]
{
    __shared__ unsigned short v_hi[2][16 * VSTR];   // [buf][n][k]; n>=BB stays 0
    __shared__ unsigned short v_lo[2][16 * VSTR];
    __shared__ float part_s[BB * GB];               // [b][g*128+j] gate pre-acts
    __shared__ float z_s[BB][64];

    const int t    = threadIdx.x;      // 512 threads = 8 waves
    const int lane = t & 63;
    const int wv   = t >> 6;           // 0..7: owns units j in [wv*16, wv*16+16)
    const int ncol = lane & 15;        // batch col (0..3 real)
    const int quad = lane >> 4;
    const int b0   = blockIdx.x * BB;
    const int j0   = wv * 16 + quad * 4;   // this lane's 4 unit-rows (C layout)

    // ---- persistent A-fragments: gate g tile = rows g*128 + wv*16 .. +15 ----
    short8 A_hi[4][NKT], A_lo[4][NKT];
    #pragma unroll
    for (int g = 0; g < 4; ++g) {
        const int row = g * HID + wv * 16 + ncol;
        #pragma unroll
        for (int kt = 0; kt < NKT; ++kt) {
            short8 hi, lo;
            #pragma unroll
            for (int j = 0; j < 8; ++j) {
                const int k = kt * 32 + quad * 8 + j;
                float w = 0.0f;
                if (k < INP)            w = W_ih[row * INP + k];
                else if (k < INP + HID) w = W_hh[row * HID + (k - INP)];
                const unsigned short h16 = f2bf(w);
                hi[j] = (short)h16;
                lo[j] = (short)f2bf(w - bf2f(h16));
            }
            A_hi[g][kt] = hi;
            A_lo[g][kt] = lo;
        }
    }

    // consumer role: thread t owns (batch ub = t>>7, unit uj = t&127)
    const int ub = t >> 7, uj = t & 127;
    const float bias_i = b_ih[0 * HID + uj] + b_hh[0 * HID + uj];
    const float bias_f = b_ih[1 * HID + uj] + b_hh[1 * HID + uj];
    const float bias_g = b_ih[2 * HID + uj] + b_hh[2 * HID + uj];
    const float bias_o = b_ih[3 * HID + uj] + b_hh[3 * HID + uj];
    float c_reg = 0.0f;

    // x-staging role: t<48 handles batch xb, k-pair kk*2
    const int xb = t / 12;
    const int kk = t - xb * 12;

    // ---- init: zero both buffers (cols >= BB and pads stay 0), stage x(0) ----
    for (int i = t; i < 16 * VSTR; i += 512) {
        v_hi[0][i] = 0; v_lo[0][i] = 0; v_hi[1][i] = 0; v_lo[1][i] = 0;
    }
    __syncthreads();
    if (t < 48) {
        const float2 xv = *(const float2*)(x + ((size_t)(b0 + xb) * TSTEPS) * INP + kk * 2);
        const unsigned short h0 = f2bf(xv.x), h1 = f2bf(xv.y);
        *(unsigned*)&v_hi[0][xb * VSTR + kk * 2] = (unsigned)h0 | ((unsigned)h1 << 16);
        *(unsigned*)&v_lo[0][xb * VSTR + kk * 2] =
            (unsigned)f2bf(xv.x - bf2f(h0)) | ((unsigned)f2bf(xv.y - bf2f(h1)) << 16);
    }
    // prime distance-2 x queue: xq = x(1)
    float2 xq = {0.f, 0.f};
    if (t < 48) {
        xq = *(const float2*)(x + ((size_t)(b0 + xb) * TSTEPS + 1) * INP + kk * 2);
    }
    __syncthreads();

    // ---- recurrence: 2 barriers per ts (redistribution) ----
    for (int ts = 0; ts < TSTEPS; ++ts) {
        const int pb = ts & 1, nb = pb ^ 1;

        // top: issue x(ts+2) load; stage x(ts+1)=xq into nb (read only next ts)
        float2 xn = {0.f, 0.f};
        if (t < 48) {
            const int tsn = (ts + 2 < TSTEPS) ? ts + 2 : TSTEPS - 1;
            xn = *(const float2*)(x + ((size_t)(b0 + xb) * TSTEPS + tsn) * INP + kk * 2);
            const unsigned short h0 = f2bf(xq.x), h1 = f2bf(xq.y);
            *(unsigned*)&v_hi[nb][xb * VSTR + kk * 2] = (unsigned)h0 | ((unsigned)h1 << 16);
            *(unsigned*)&v_lo[nb][xb * VSTR + kk * 2] =
                (unsigned)f2bf(xq.x - bf2f(h0)) | ((unsigned)f2bf(xq.y - bf2f(h1)) << 16);
        }

        // MFMA phase: 60 mfma into 4 accumulators (AGPR)
        const unsigned short* vh = v_hi[pb];
        const unsigned short* vl = v_lo[pb];
        f32x4 ai = {0.f, 0.f, 0.f, 0.f}, af = ai, ag = ai, ao = ai;
        #pragma unroll
        for (int kt = 0; kt < NKT; ++kt) {
            const int voff = ncol * VSTR + kt * 32 + quad * 8;
            const short8 bh = *(const short8*)(vh + voff);
            const short8 bl = *(const short8*)(vl + voff);
            ai = __builtin_amdgcn_mfma_f32_16x16x32_bf16(A_hi[0][kt], bh, ai, 0, 0, 0);
            af = __builtin_amdgcn_mfma_f32_16x16x32_bf16(A_hi[1][kt], bh, af, 0, 0, 0);
            ag = __builtin_amdgcn_mfma_f32_16x16x32_bf16(A_hi[2][kt], bh, ag, 0, 0, 0);
            ao = __builtin_amdgcn_mfma_f32_16x16x32_bf16(A_hi[3][kt], bh, ao, 0, 0, 0);
            ai = __builtin_amdgcn_mfma_f32_16x16x32_bf16(A_lo[0][kt], bh, ai, 0, 0, 0);
            af = __builtin_amdgcn_mfma_f32_16x16x32_bf16(A_lo[1][kt], bh, af, 0, 0, 0);
            ag = __builtin_amdgcn_mfma_f32_16x16x32_bf16(A_lo[2][kt], bh, ag, 0, 0, 0);
            ao = __builtin_amdgcn_mfma_f32_16x16x32_bf16(A_lo[3][kt], bh, ao, 0, 0, 0);
            ai = __builtin_amdgcn_mfma_f32_16x16x32_bf16(A_hi[0][kt], bl, ai, 0, 0, 0);
            af = __builtin_amdgcn_mfma_f32_16x16x32_bf16(A_hi[1][kt], bl, af, 0, 0, 0);
            ag = __builtin_amdgcn_mfma_f32_16x16x32_bf16(A_hi[2][kt], bl, ag, 0, 0, 0);
            ao = __builtin_amdgcn_mfma_f32_16x16x32_bf16(A_hi[3][kt], bl, ao, 0, 0, 0);
        }

        // producer: publish gate pre-acts for real batch cols (f32x4, <=2-way banks)
        if (ncol < BB) {
            float* gp = part_s + ncol * GB + j0;
            *(f32x4*)(gp + 0 * HID) = ai;
            *(f32x4*)(gp + 1 * HID) = af;
            *(f32x4*)(gp + 2 * HID) = ag;
            *(f32x4*)(gp + 3 * HID) = ao;
        }
        __syncthreads();

        // consumer: exactly ONE cell update per thread (512 = BB*HID pairs)
        {
            const float gi = sigm_f(part_s[ub * GB + 0 * HID + uj] + bias_i);
            const float gf = sigm_f(part_s[ub * GB + 1 * HID + uj] + bias_f);
            const float gg = tanh_f(part_s[ub * GB + 2 * HID + uj] + bias_g);
            const float go = sigm_f(part_s[ub * GB + 3 * HID + uj] + bias_o);
            c_reg = gf * c_reg + gi * gg;
            const float h = go * tanh_f(c_reg);
            const unsigned short hh16 = f2bf(h);
            v_hi[nb][ub * VSTR + INP + uj] = hh16;
            v_lo[nb][ub * VSTR + INP + uj] = f2bf(h - bf2f(hh16));
        }

        // roll x queue
        if (t < 48) xq = xn;
        __syncthreads();
    }

    // ---- FC head: final h is in buffer 0 (ts=511 -> nb=0) ----
    if (t < 256) {
        const int b = t >> 6, u = t & 63;
        const float* w = W1 + u * 130;
        float a = b1[u];
        #pragma unroll 16
        for (int k = 0; k < HID; ++k) {
            const float hv = bf2f(v_hi[0][b * VSTR + INP + k]) + bf2f(v_lo[0][b * VSTR + INP + k]);
            a += fmaxf(hv, 0.0f) * w[k];
        }
        const float a0 = addin[(size_t)(b0 + b) * 2 + 0];
        const float a1 = addin[(size_t)(b0 + b) * 2 + 1];
        a += fmaxf(a0, 0.0f) * w[128] + fmaxf(a1, 0.0f) * w[129];
        z_s[b][u] = fmaxf(a, 0.0f);
    }
    __syncthreads();
    if (t < 12) {
        const int b = t / 3, o = t - 3 * b;
        const float* w = W2 + o * 64;
        float a = b2[o];
        #pragma unroll
        for (int k = 0; k < 64; ++k)
            a += z_s[b][k] * w[k];
        out[(size_t)(b0 + b) * 3 + o] = a;
    }
}

extern "C" void kernel_launch(void* const* d_in, const int* in_sizes, int n_in,
                              void* d_out, int out_size, void* d_ws, size_t ws_size,
                              hipStream_t stream) {
    const float* x     = (const float*)d_in[0];
    const float* addin = (const float*)d_in[1];
    const float* W_ih  = (const float*)d_in[2];
    const float* W_hh  = (const float*)d_in[3];
    const float* b_ih  = (const float*)d_in[4];
    const float* b_hh  = (const float*)d_in[5];
    const float* W1    = (const float*)d_in[6];
    const float* b1    = (const float*)d_in[7];
    const float* W2    = (const float*)d_in[8];
    const float* b2    = (const float*)d_in[9];
    float* outp        = (float*)d_out;

    const int B = in_sizes[0] / (TSTEPS * INP);   // 1024
    const int grid = B / BB;                      // 256 blocks (1 per CU)

    lstm_fused<<<grid, 512, 0, stream>>>(x, addin, W_ih, W_hh, b_ih, b_hh,
                                         W1, b1, W2, b2, outp);
}

// Round 8
// 749.115 us; speedup vs baseline: 1.7384x; 1.2283x over previous
//
#include <hip/hip_runtime.h>
#include <cstdint>
#include <cstddef>

#define TSTEPS 512
#define INP    24
#define HID    128
#define BB     4      // batch elems per block; 256 blocks (1/CU)
#define NKT    5      // K = 24 x + 128 h + 8 pad = 160 = 5 tiles of 32
#define VSTR   168    // v[] column stride in ushorts
#define GB     520    // part_s batch stride in floats; 520 mod 32 == 8 -> <=2-way banks

typedef __attribute__((ext_vector_type(8))) short short8;   // 8 x bf16 (4 VGPRs)
typedef __attribute__((ext_vector_type(4))) float f32x4;

__device__ __forceinline__ float sigm_f(float v) {
    return 1.0f / (1.0f + __expf(-v));
}
__device__ __forceinline__ float tanh_f(float v) {
    float a = fabsf(v);
    float e = __expf(-2.0f * a);
    float r = (1.0f - e) / (1.0f + e);
    return v < 0.0f ? -r : r;
}
__device__ __forceinline__ unsigned short f2bf(float f) {
    unsigned u = __float_as_uint(f);
    return (unsigned short)((u + 0x7fffu + ((u >> 16) & 1u)) >> 16);
}
__device__ __forceinline__ float bf2f(unsigned short h) {
    return __uint_as_float(((unsigned)h) << 16);
}

// ROUND LESSONS ENCODED:
//  R1: VGPR-cap betrayal -> scratch spill shows as WRITE_SIZE GBs. Watch it.
//  R2: runtime-varying index into per-thread arrays demotes to memory. All
//      A-frag indices compile-time below.
//  R3: fp32 VALU ~3x too slow; use MFMA.
//  R4/R5: total time == per-block time (blocks run concurrently, CU count free).
//  R6 MODEL FIX: mfma_16x16x32_bf16 ~19.4 cyc/SIMD (4.85 is per-CU). Phases sum.
//  R7: structure validated — 4312 cyc/ts = 2328 MFMA drain + ~1980 other; LDS
//      layouts are at the conflict minimum (4.2e7 counter = intrinsic b128 cost).
//  R8 (this): 2-PASS split — W kept exact (hi+lo bf16), state/x rounded to bf16
//      (v_lo ELIMINATED). Error = W·(v - bf16(v)): incoherent per-step rounding
//      noise ~5e-4..1e-3 final, inside the 2.03e-3 threshold. Drain 2328->1552,
//      B-reads halved, lo-staging gone.
//
// Per ts: gates[512 x 16] = (Whi+Wlo)[512 x 160] @ vh[160 x 16], batch cols 0..3
// real, cols 4..15 permanently zero. mfma_f32_16x16x32_bf16:
//   A-frag: lane holds A[m=lane&15][k=quad*8+j]
//   B-frag: lane holds B[k=quad*8+j][n=lane&15]
//   C/D:    col=lane&15, row=quad*4+reg
__global__ __launch_bounds__(512) __attribute__((amdgpu_waves_per_eu(2, 2)))
void lstm_fused(
    const float* __restrict__ x,      // [B, T, 24]
    const float* __restrict__ addin,  // [B, 2]
    const float* __restrict__ W_ih,   // [512, 24]
    const float* __restrict__ W_hh,   // [512, 128]
    const float* __restrict__ b_ih,   // [512]
    const float* __restrict__ b_hh,   // [512]
    const float* __restrict__ W1,     // [64, 130]
    const float* __restrict__ b1,     // [64]
    const float* __restrict__ W2,     // [3, 64]
    const float* __restrict__ b2,     // [3]
    float* __restrict__ out)          // [B, 3]
{
    __shared__ unsigned short v_hi[2][16 * VSTR];   // [buf][n][k]; n>=BB stays 0
    __shared__ float part_s[BB * GB];               // [b][g*128+j] gate pre-acts
    __shared__ float z_s[BB][64];

    const int t    = threadIdx.x;      // 512 threads = 8 waves
    const int lane = t & 63;
    const int wv   = t >> 6;           // 0..7: owns gate rows wv*16..+15 (x4 gates)
    const int ncol = lane & 15;        // batch col (0..3 real)
    const int quad = lane >> 4;
    const int b0   = blockIdx.x * BB;
    const int j0   = wv * 16 + quad * 4;   // this lane's 4 unit-rows (C layout)

    // ---- persistent A-fragments: gate g tile = rows g*128 + wv*16 .. +15 ----
    short8 A_hi[4][NKT], A_lo[4][NKT];
    #pragma unroll
    for (int g = 0; g < 4; ++g) {
        const int row = g * HID + wv * 16 + ncol;
        #pragma unroll
        for (int kt = 0; kt < NKT; ++kt) {
            short8 hi, lo;
            #pragma unroll
            for (int j = 0; j < 8; ++j) {
                const int k = kt * 32 + quad * 8 + j;
                float w = 0.0f;
                if (k < INP)            w = W_ih[row * INP + k];
                else if (k < INP + HID) w = W_hh[row * HID + (k - INP)];
                const unsigned short h16 = f2bf(w);
                hi[j] = (short)h16;
                lo[j] = (short)f2bf(w - bf2f(h16));
            }
            A_hi[g][kt] = hi;
            A_lo[g][kt] = lo;
        }
    }

    // consumer role: thread t owns (batch ub = t>>7, unit uj = t&127)
    const int ub = t >> 7, uj = t & 127;
    const float bias_i = b_ih[0 * HID + uj] + b_hh[0 * HID + uj];
    const float bias_f = b_ih[1 * HID + uj] + b_hh[1 * HID + uj];
    const float bias_g = b_ih[2 * HID + uj] + b_hh[2 * HID + uj];
    const float bias_o = b_ih[3 * HID + uj] + b_hh[3 * HID + uj];
    float c_reg = 0.0f;

    // x-staging role: t<48 handles batch xb, k-pair kk*2
    const int xb = t / 12;
    const int kk = t - xb * 12;

    // ---- init: zero both buffers (cols >= BB and pads stay 0), stage x(0) ----
    for (int i = t; i < 16 * VSTR; i += 512) {
        v_hi[0][i] = 0; v_hi[1][i] = 0;
    }
    __syncthreads();
    if (t < 48) {
        const float2 xv = *(const float2*)(x + ((size_t)(b0 + xb) * TSTEPS) * INP + kk * 2);
        *(unsigned*)&v_hi[0][xb * VSTR + kk * 2] =
            (unsigned)f2bf(xv.x) | ((unsigned)f2bf(xv.y) << 16);
    }
    // prime distance-2 x queue: xq = x(1)
    float2 xq = {0.f, 0.f};
    if (t < 48) {
        xq = *(const float2*)(x + ((size_t)(b0 + xb) * TSTEPS + 1) * INP + kk * 2);
    }
    __syncthreads();

    // ---- recurrence: 2 barriers per ts (redistribution) ----
    for (int ts = 0; ts < TSTEPS; ++ts) {
        const int pb = ts & 1, nb = pb ^ 1;

        // top: issue x(ts+2) load; stage x(ts+1)=xq into nb (read only next ts)
        float2 xn = {0.f, 0.f};
        if (t < 48) {
            const int tsn = (ts + 2 < TSTEPS) ? ts + 2 : TSTEPS - 1;
            xn = *(const float2*)(x + ((size_t)(b0 + xb) * TSTEPS + tsn) * INP + kk * 2);
            *(unsigned*)&v_hi[nb][xb * VSTR + kk * 2] =
                (unsigned)f2bf(xq.x) | ((unsigned)f2bf(xq.y) << 16);
        }

        // MFMA phase: 2 passes (W hi + W lo) x 5 kt x 4 gates = 40 mfma
        const unsigned short* vh = v_hi[pb];
        f32x4 ai = {0.f, 0.f, 0.f, 0.f}, af = ai, ag = ai, ao = ai;
        #pragma unroll
        for (int kt = 0; kt < NKT; ++kt) {
            const int voff = ncol * VSTR + kt * 32 + quad * 8;
            const short8 bh = *(const short8*)(vh + voff);
            ai = __builtin_amdgcn_mfma_f32_16x16x32_bf16(A_hi[0][kt], bh, ai, 0, 0, 0);
            af = __builtin_amdgcn_mfma_f32_16x16x32_bf16(A_hi[1][kt], bh, af, 0, 0, 0);
            ag = __builtin_amdgcn_mfma_f32_16x16x32_bf16(A_hi[2][kt], bh, ag, 0, 0, 0);
            ao = __builtin_amdgcn_mfma_f32_16x16x32_bf16(A_hi[3][kt], bh, ao, 0, 0, 0);
            ai = __builtin_amdgcn_mfma_f32_16x16x32_bf16(A_lo[0][kt], bh, ai, 0, 0, 0);
            af = __builtin_amdgcn_mfma_f32_16x16x32_bf16(A_lo[1][kt], bh, af, 0, 0, 0);
            ag = __builtin_amdgcn_mfma_f32_16x16x32_bf16(A_lo[2][kt], bh, ag, 0, 0, 0);
            ao = __builtin_amdgcn_mfma_f32_16x16x32_bf16(A_lo[3][kt], bh, ao, 0, 0, 0);
        }

        // producer: publish gate pre-acts for real batch cols (f32x4, <=2-way banks)
        if (ncol < BB) {
            float* gp = part_s + ncol * GB + j0;
            *(f32x4*)(gp + 0 * HID) = ai;
            *(f32x4*)(gp + 1 * HID) = af;
            *(f32x4*)(gp + 2 * HID) = ag;
            *(f32x4*)(gp + 3 * HID) = ao;
        }
        __syncthreads();

        // consumer: exactly ONE cell update per thread (512 = BB*HID pairs)
        {
            const float gi = sigm_f(part_s[ub * GB + 0 * HID + uj] + bias_i);
            const float gf = sigm_f(part_s[ub * GB + 1 * HID + uj] + bias_f);
            const float gg = tanh_f(part_s[ub * GB + 2 * HID + uj] + bias_g);
            const float go = sigm_f(part_s[ub * GB + 3 * HID + uj] + bias_o);
            c_reg = gf * c_reg + gi * gg;
            const float h = go * tanh_f(c_reg);
            v_hi[nb][ub * VSTR + INP + uj] = f2bf(h);
        }

        // roll x queue
        if (t < 48) xq = xn;
        __syncthreads();
    }

    // ---- FC head: final h is in buffer 0 (ts=511 -> nb=0); h is bf16 now ----
    if (t < 256) {
        const int b = t >> 6, u = t & 63;
        const float* w = W1 + u * 130;
        float a = b1[u];
        #pragma unroll 16
        for (int k = 0; k < HID; ++k) {
            const float hv = bf2f(v_hi[0][b * VSTR + INP + k]);
            a += fmaxf(hv, 0.0f) * w[k];
        }
        const float a0 = addin[(size_t)(b0 + b) * 2 + 0];
        const float a1 = addin[(size_t)(b0 + b) * 2 + 1];
        a += fmaxf(a0, 0.0f) * w[128] + fmaxf(a1, 0.0f) * w[129];
        z_s[b][u] = fmaxf(a, 0.0f);
    }
    __syncthreads();
    if (t < 12) {
        const int b = t / 3, o = t - 3 * b;
        const float* w = W2 + o * 64;
        float a = b2[o];
        #pragma unroll
        for (int k = 0; k < 64; ++k)
            a += z_s[b][k] * w[k];
        out[(size_t)(b0 + b) * 3 + o] = a;
    }
}

extern "C" void kernel_launch(void* const* d_in, const int* in_sizes, int n_in,
                              void* d_out, int out_size, void* d_ws, size_t ws_size,
                              hipStream_t stream) {
    const float* x     = (const float*)d_in[0];
    const float* addin = (const float*)d_in[1];
    const float* W_ih  = (const float*)d_in[2];
    const float* W_hh  = (const float*)d_in[3];
    const float* b_ih  = (const float*)d_in[4];
    const float* b_hh  = (const float*)d_in[5];
    const float* W1    = (const float*)d_in[6];
    const float* b1    = (const float*)d_in[7];
    const float* W2    = (const float*)d_in[8];
    const float* b2    = (const float*)d_in[9];
    float* outp        = (float*)d_out;

    const int B = in_sizes[0] / (TSTEPS * INP);   // 1024
    const int grid = B / BB;                      // 256 blocks (1 per CU)

    lstm_fused<<<grid, 512, 0, stream>>>(x, addin, W_ih, W_hh, b_ih, b_hh,
                                         W1, b1, W2, b2, outp);
}

// Round 9
// 619.605 us; speedup vs baseline: 2.1018x; 1.2090x over previous
//
#include <hip/hip_runtime.h>
#include <cstdint>
#include <cstddef>

#define TSTEPS 512
#define INP    24
#define HID    128
#define BB     4      // batch elems per block; 256 blocks (1/CU)
#define NKT    5      // K = 24 x + 128 h + 8 pad = 160 = 5 tiles of 32
#define VSTR   168    // v[] column stride in fp16 elems
#define GB     520    // part_s batch stride in floats; 520 mod 32 == 8 -> <=2-way banks

typedef __attribute__((ext_vector_type(8))) _Float16 half8;   // 8 x fp16 (4 VGPRs)
typedef __attribute__((ext_vector_type(4))) float f32x4;

__device__ __forceinline__ float sigm_f(float v) {
    return 1.0f / (1.0f + __expf(-v));
}
__device__ __forceinline__ float tanh_f(float v) {
    float a = fabsf(v);
    float e = __expf(-2.0f * a);
    float r = (1.0f - e) / (1.0f + e);
    return v < 0.0f ? -r : r;
}
__device__ __forceinline__ unsigned pack2h(float a, float b) {
    union { _Float16 h[2]; unsigned u; } z;
    z.h[0] = (_Float16)a; z.h[1] = (_Float16)b;   // v_cvt_f16_f32, RTN
    return z.u;
}

// ROUND LESSONS ENCODED:
//  R1: VGPR-cap betrayal -> scratch spill shows as WRITE_SIZE GBs. Watch it.
//  R2: runtime-varying index into per-thread arrays demotes to memory. All
//      A-frag indices compile-time below.
//  R3: fp32 VALU ~3x too slow; use MFMA.
//  R4/R5: total time == per-block time (blocks run concurrently, CU count free).
//  R6 MODEL FIX: mfma ~19.4 cyc/SIMD (4.85 is per-CU). Phases sum.
//  R7: LDS layouts at conflict minimum; 4.2e7 counter = intrinsic b128 cost.
//  R8 MODEL FIX: LDS pipe is PER-CU (shared by 4 SIMDs) — redistribution round
//      trips ~1000+ LDS cyc/ts, half of it on the serial path.
//  R9 (this): SINGLE-PASS FP16. fp16 mantissa 2^-11: W rel-err 4x finer than
//      bf16, state rounding 8x finer than R8's bf16 state. Ranges safe
//      (|W|<=0.088, |h|<1, x~N(0,1) << 65504). Halves mfma count (160/blk/ts)
//      AND A-frag registers (80). Same MFMA rate as bf16.
//
// Per ts: gates[512 x 16] = W[512 x 160] @ v[160 x 16], batch cols 0..3 real.
// mfma_f32_16x16x32_f16:
//   A-frag: lane holds A[m=lane&15][k=quad*8+j]
//   B-frag: lane holds B[k=quad*8+j][n=lane&15]
//   C/D:    col=lane&15, row=quad*4+reg
__global__ __launch_bounds__(512) __attribute__((amdgpu_waves_per_eu(2, 2)))
void lstm_fused(
    const float* __restrict__ x,      // [B, T, 24]
    const float* __restrict__ addin,  // [B, 2]
    const float* __restrict__ W_ih,   // [512, 24]
    const float* __restrict__ W_hh,   // [512, 128]
    const float* __restrict__ b_ih,   // [512]
    const float* __restrict__ b_hh,   // [512]
    const float* __restrict__ W1,     // [64, 130]
    const float* __restrict__ b1,     // [64]
    const float* __restrict__ W2,     // [3, 64]
    const float* __restrict__ b2,     // [3]
    float* __restrict__ out)          // [B, 3]
{
    __shared__ _Float16 v_s[2][16 * VSTR];   // [buf][n][k]; n>=BB stays 0
    __shared__ float part_s[BB * GB];        // [b][g*128+j] gate pre-acts
    __shared__ float z_s[BB][64];

    const int t    = threadIdx.x;      // 512 threads = 8 waves
    const int lane = t & 63;
    const int wv   = t >> 6;           // 0..7: owns unit rows wv*16..+15 (x4 gates)
    const int ncol = lane & 15;        // batch col (0..3 real)
    const int quad = lane >> 4;
    const int b0   = blockIdx.x * BB;
    const int j0   = wv * 16 + quad * 4;   // this lane's 4 unit-rows (C layout)

    // ---- persistent A-fragments (fp16, single precision level) ----
    half8 A_w[4][NKT];
    #pragma unroll
    for (int g = 0; g < 4; ++g) {
        const int row = g * HID + wv * 16 + ncol;
        #pragma unroll
        for (int kt = 0; kt < NKT; ++kt) {
            half8 frag;
            #pragma unroll
            for (int j = 0; j < 8; ++j) {
                const int k = kt * 32 + quad * 8 + j;
                float w = 0.0f;
                if (k < INP)            w = W_ih[row * INP + k];
                else if (k < INP + HID) w = W_hh[row * HID + (k - INP)];
                frag[j] = (_Float16)w;
            }
            A_w[g][kt] = frag;
        }
    }

    // consumer role: thread t owns (batch ub = t>>7, unit uj = t&127)
    const int ub = t >> 7, uj = t & 127;
    const float bias_i = b_ih[0 * HID + uj] + b_hh[0 * HID + uj];
    const float bias_f = b_ih[1 * HID + uj] + b_hh[1 * HID + uj];
    const float bias_g = b_ih[2 * HID + uj] + b_hh[2 * HID + uj];
    const float bias_o = b_ih[3 * HID + uj] + b_hh[3 * HID + uj];
    float c_reg = 0.0f;

    // x-staging role: t<48 handles batch xb, k-pair kk*2
    const int xb = t / 12;
    const int kk = t - xb * 12;

    // ---- init: zero both buffers (cols >= BB and pads stay 0), stage x(0) ----
    for (int i = t; i < 16 * VSTR; i += 512) {
        v_s[0][i] = (_Float16)0.0f; v_s[1][i] = (_Float16)0.0f;
    }
    __syncthreads();
    if (t < 48) {
        const float2 xv = *(const float2*)(x + ((size_t)(b0 + xb) * TSTEPS) * INP + kk * 2);
        *(unsigned*)&v_s[0][xb * VSTR + kk * 2] = pack2h(xv.x, xv.y);
    }
    // prime distance-2 x queue: xq = x(1)
    float2 xq = {0.f, 0.f};
    if (t < 48) {
        xq = *(const float2*)(x + ((size_t)(b0 + xb) * TSTEPS + 1) * INP + kk * 2);
    }
    __syncthreads();

    // ---- recurrence: 2 barriers per ts (redistribution) ----
    for (int ts = 0; ts < TSTEPS; ++ts) {
        const int pb = ts & 1, nb = pb ^ 1;

        // top: issue x(ts+2) load; stage x(ts+1)=xq into nb (read only next ts)
        float2 xn = {0.f, 0.f};
        if (t < 48) {
            const int tsn = (ts + 2 < TSTEPS) ? ts + 2 : TSTEPS - 1;
            xn = *(const float2*)(x + ((size_t)(b0 + xb) * TSTEPS + tsn) * INP + kk * 2);
            *(unsigned*)&v_s[nb][xb * VSTR + kk * 2] = pack2h(xq.x, xq.y);
        }

        // MFMA phase: 1 pass x 5 kt x 4 gates = 20 mfma per wave
        const _Float16* vh = v_s[pb];
        f32x4 ai = {0.f, 0.f, 0.f, 0.f}, af = ai, ag = ai, ao = ai;
        #pragma unroll
        for (int kt = 0; kt < NKT; ++kt) {
            const half8 bh = *(const half8*)(vh + ncol * VSTR + kt * 32 + quad * 8);
            ai = __builtin_amdgcn_mfma_f32_16x16x32_f16(A_w[0][kt], bh, ai, 0, 0, 0);
            af = __builtin_amdgcn_mfma_f32_16x16x32_f16(A_w[1][kt], bh, af, 0, 0, 0);
            ag = __builtin_amdgcn_mfma_f32_16x16x32_f16(A_w[2][kt], bh, ag, 0, 0, 0);
            ao = __builtin_amdgcn_mfma_f32_16x16x32_f16(A_w[3][kt], bh, ao, 0, 0, 0);
        }

        // producer: publish gate pre-acts for real batch cols (f32x4, <=2-way banks)
        if (ncol < BB) {
            float* gp = part_s + ncol * GB + j0;
            *(f32x4*)(gp + 0 * HID) = ai;
            *(f32x4*)(gp + 1 * HID) = af;
            *(f32x4*)(gp + 2 * HID) = ag;
            *(f32x4*)(gp + 3 * HID) = ao;
        }
        __syncthreads();

        // consumer: exactly ONE cell update per thread (512 = BB*HID pairs)
        {
            const float gi = sigm_f(part_s[ub * GB + 0 * HID + uj] + bias_i);
            const float gf = sigm_f(part_s[ub * GB + 1 * HID + uj] + bias_f);
            const float gg = tanh_f(part_s[ub * GB + 2 * HID + uj] + bias_g);
            const float go = sigm_f(part_s[ub * GB + 3 * HID + uj] + bias_o);
            c_reg = gf * c_reg + gi * gg;
            const float h = go * tanh_f(c_reg);
            v_s[nb][ub * VSTR + INP + uj] = (_Float16)h;
        }

        // roll x queue
        if (t < 48) xq = xn;
        __syncthreads();
    }

    // ---- FC head: final h is in buffer 0 (ts=511 -> nb=0); h is fp16 ----
    if (t < 256) {
        const int b = t >> 6, u = t & 63;
        const float* w = W1 + u * 130;
        float a = b1[u];
        #pragma unroll 16
        for (int k = 0; k < HID; ++k) {
            const float hv = (float)v_s[0][b * VSTR + INP + k];
            a += fmaxf(hv, 0.0f) * w[k];
        }
        const float a0 = addin[(size_t)(b0 + b) * 2 + 0];
        const float a1 = addin[(size_t)(b0 + b) * 2 + 1];
        a += fmaxf(a0, 0.0f) * w[128] + fmaxf(a1, 0.0f) * w[129];
        z_s[b][u] = fmaxf(a, 0.0f);
    }
    __syncthreads();
    if (t < 12) {
        const int b = t / 3, o = t - 3 * b;
        const float* w = W2 + o * 64;
        float a = b2[o];
        #pragma unroll
        for (int k = 0; k < 64; ++k)
            a += z_s[b][k] * w[k];
        out[(size_t)(b0 + b) * 3 + o] = a;
    }
}

extern "C" void kernel_launch(void* const* d_in, const int* in_sizes, int n_in,
                              void* d_out, int out_size, void* d_ws, size_t ws_size,
                              hipStream_t stream) {
    const float* x     = (const float*)d_in[0];
    const float* addin = (const float*)d_in[1];
    const float* W_ih  = (const float*)d_in[2];
    const float* W_hh  = (const float*)d_in[3];
    const float* b_ih  = (const float*)d_in[4];
    const float* b_hh  = (const float*)d_in[5];
    const float* W1    = (const float*)d_in[6];
    const float* b1    = (const float*)d_in[7];
    const float* W2    = (const float*)d_in[8];
    const float* b2    = (const float*)d_in[9];
    float* outp        = (float*)d_out;

    const int B = in_sizes[0] / (TSTEPS * INP);   // 1024
    const int grid = B / BB;                      // 256 blocks (1 per CU)

    lstm_fused<<<grid, 512, 0, stream>>>(x, addin, W_ih, W_hh, b_ih, b_hh,
                                         W1, b1, W2, b2, outp);
}